// Round 1
// baseline (171.396 us; speedup 1.0000x reference)
//
#include <hip/hip_runtime.h>

#define H_IMG 1080
#define W_IMG 1920
#define HW_PIX (H_IMG * W_IMG)
#define GRID_Y 16
#define GRID_X 16
#define GRID_L 8
#define CELL_F 12  // floats per grid cell

__global__ __launch_bounds__(256) void bilateral_grid_kernel(
    const float* __restrict__ rgb,    // (3, H, W)
    const float* __restrict__ grids,  // (NUM, 16, 16, 8, 12)
    const int* __restrict__ idxp,     // scalar
    float* __restrict__ out)          // [affine (HW*12) | res (HW*3)]
{
    int p = blockIdx.x * blockDim.x + threadIdx.x;
    if (p >= HW_PIX) return;

    int y = p / W_IMG;
    int x = p - y * W_IMG;

    const float* grid = grids + (size_t)idxp[0] * (GRID_Y * GRID_X * GRID_L * CELL_F);

    float r = rgb[p];
    float g = rgb[HW_PIX + p];
    float b = rgb[2 * HW_PIX + p];

    float gray = 0.299f * r + 0.587f * g + 0.114f * b;

    // align_corners-style coords: linspace(0, Hg-1, Hi) -> y * (Hg-1)/(Hi-1)
    float gy = (float)y * (15.0f / 1079.0f);
    float gx = (float)x * (15.0f / 1919.0f);
    float gz = fminf(fmaxf(gray, 0.0f), 1.0f) * 7.0f;

    float fy = floorf(gy), wy = gy - fy;
    float fx = floorf(gx), wx = gx - fx;
    float fz = floorf(gz), wz = gz - fz;

    int y0 = min(max((int)fy, 0), GRID_Y - 1); int y1 = min(y0 + 1, GRID_Y - 1);
    int x0 = min(max((int)fx, 0), GRID_X - 1); int x1 = min(x0 + 1, GRID_X - 1);
    int z0 = min(max((int)fz, 0), GRID_L - 1); int z1 = min(z0 + 1, GRID_L - 1);

    int   ys[2] = {y0, y1};  float wys[2] = {1.0f - wy, wy};
    int   xs[2] = {x0, x1};  float wxs[2] = {1.0f - wx, wx};
    int   zs[2] = {z0, z1};  float wzs[2] = {1.0f - wz, wz};

    float4 acc0 = make_float4(0.f, 0.f, 0.f, 0.f);
    float4 acc1 = make_float4(0.f, 0.f, 0.f, 0.f);
    float4 acc2 = make_float4(0.f, 0.f, 0.f, 0.f);

#pragma unroll
    for (int a = 0; a < 2; ++a) {
#pragma unroll
        for (int c = 0; c < 2; ++c) {
#pragma unroll
            for (int d = 0; d < 2; ++d) {
                float w = wys[a] * wxs[c] * wzs[d];
                const float4* cell = (const float4*)(grid +
                    (size_t)((ys[a] * GRID_X + xs[c]) * GRID_L + zs[d]) * CELL_F);
                float4 c0 = cell[0];
                float4 c1 = cell[1];
                float4 c2 = cell[2];
                acc0.x = fmaf(w, c0.x, acc0.x);
                acc0.y = fmaf(w, c0.y, acc0.y);
                acc0.z = fmaf(w, c0.z, acc0.z);
                acc0.w = fmaf(w, c0.w, acc0.w);
                acc1.x = fmaf(w, c1.x, acc1.x);
                acc1.y = fmaf(w, c1.y, acc1.y);
                acc1.z = fmaf(w, c1.z, acc1.z);
                acc1.w = fmaf(w, c1.w, acc1.w);
                acc2.x = fmaf(w, c2.x, acc2.x);
                acc2.y = fmaf(w, c2.y, acc2.y);
                acc2.z = fmaf(w, c2.z, acc2.z);
                acc2.w = fmaf(w, c2.w, acc2.w);
            }
        }
    }

    // affine_mat output: per pixel 12 contiguous floats, 48B stride (16B aligned)
    float4* ao = (float4*)out + (size_t)p * 3;
    ao[0] = acc0;
    ao[1] = acc1;
    ao[2] = acc2;

    // res_rgb = A[:, :3] @ rgb + A[:, 3]
    float res0 = fmaf(acc0.x, r, fmaf(acc0.y, g, fmaf(acc0.z, b, acc0.w)));
    float res1 = fmaf(acc1.x, r, fmaf(acc1.y, g, fmaf(acc1.z, b, acc1.w)));
    float res2 = fmaf(acc2.x, r, fmaf(acc2.y, g, fmaf(acc2.z, b, acc2.w)));

    float* ro = out + (size_t)HW_PIX * 12 + (size_t)p * 3;
    ro[0] = res0;
    ro[1] = res1;
    ro[2] = res2;
}

extern "C" void kernel_launch(void* const* d_in, const int* in_sizes, int n_in,
                              void* d_out, int out_size, void* d_ws, size_t ws_size,
                              hipStream_t stream) {
    const float* rgb   = (const float*)d_in[0];
    const float* grids = (const float*)d_in[1];
    const int*   idx   = (const int*)d_in[2];
    float*       out   = (float*)d_out;

    int threads = 256;
    int blocks = (HW_PIX + threads - 1) / threads;
    bilateral_grid_kernel<<<blocks, threads, 0, stream>>>(rgb, grids, idx, out);
}

// Round 2
// 154.006 us; speedup vs baseline: 1.1129x; 1.1129x over previous
//
#include <hip/hip_runtime.h>

#define H_IMG 1080
#define W_IMG 1920
#define HW_PIX (H_IMG * W_IMG)
#define GY 16
#define GX 16
#define GL 8
#define CF 12          // floats per grid cell
#define SEG 192        // pixels per block (3 waves); 1920 = 10*192 exactly

// Block = one image row x 192 pixels. y-interp is uniform per row; the 192-px
// span covers at most 4 grid x-cells. Stage G'[xi][z][c] = lerp_y(grid) in LDS
// (4*8*3 float4 = 1.5KB), then each pixel does 4 LDS cells instead of 8 global.
__global__ __launch_bounds__(192) void bg_kernel(
    const float* __restrict__ rgb,    // (3, H, W)
    const float* __restrict__ grids,  // (NUM, 16, 16, 8, 12)
    const int* __restrict__ idxp,
    float* __restrict__ out)          // [affine HW*12 | res HW*3]
{
    __shared__ float4 sg[96];         // [xi(4)][z(8)][c4(3)]

    const int tid = threadIdx.x;
    const int y = blockIdx.y;
    const int xbase = blockIdx.x * SEG;

    const float* grid = grids + (size_t)idxp[0] * (GY * GX * GL * CF);

    // row-uniform y interpolation
    float gyv = (float)y * (15.0f / 1079.0f);
    float fy = floorf(gyv);
    float wy = gyv - fy;
    int y0 = min(max((int)fy, 0), GY - 1);
    int y1 = min(y0 + 1, GY - 1);

    // block-uniform first x-cell
    int xc0 = (int)floorf((float)xbase * (15.0f / 1919.0f));

    if (tid < 96) {
        int xi  = tid / 24;
        int rem = tid - xi * 24;
        int z   = rem / 3;
        int c4  = rem - z * 3;
        int xc  = min(xc0 + xi, GX - 1);
        const float4* c0 = (const float4*)(grid + (size_t)((y0 * GX + xc) * GL + z) * CF) + c4;
        const float4* c1 = (const float4*)(grid + (size_t)((y1 * GX + xc) * GL + z) * CF) + c4;
        float4 a = *c0, b = *c1;
        float wy0 = 1.0f - wy;
        float4 r;
        r.x = wy0 * a.x + wy * b.x;
        r.y = wy0 * a.y + wy * b.y;
        r.z = wy0 * a.z + wy * b.z;
        r.w = wy0 * a.w + wy * b.w;
        sg[tid] = r;
    }
    __syncthreads();

    const int x = xbase + tid;          // always < 1920 (10*192 grid)
    const int p = y * W_IMG + x;

    float r = rgb[p];
    float g = rgb[HW_PIX + p];
    float b = rgb[2 * HW_PIX + p];

    float gray = 0.299f * r + 0.587f * g + 0.114f * b;

    float gxv = (float)x * (15.0f / 1919.0f);
    float fx = floorf(gxv), wx = gxv - fx;
    float gz = fminf(fmaxf(gray, 0.0f), 1.0f) * 7.0f;
    float fz = floorf(gz), wz = gz - fz;

    int x0g = min(max((int)fx, 0), GX - 1);
    int x1g = min(x0g + 1, GX - 1);
    int xi0 = x0g - xc0;                // in [0,3]
    int xi1 = x1g - xc0;                // in [0,3]
    int z0 = min(max((int)fz, 0), GL - 1);
    int z1 = min(z0 + 1, GL - 1);

    float w00 = (1.0f - wx) * (1.0f - wz);
    float w01 = (1.0f - wx) * wz;
    float w10 = wx * (1.0f - wz);
    float w11 = wx * wz;

    const float4* A = sg + (xi0 * 24 + z0 * 3);
    const float4* B = sg + (xi0 * 24 + z1 * 3);
    const float4* C = sg + (xi1 * 24 + z0 * 3);
    const float4* D = sg + (xi1 * 24 + z1 * 3);

    float4 acc[3];
#pragma unroll
    for (int j = 0; j < 3; ++j) {
        float4 va = A[j], vb = B[j], vc = C[j], vd = D[j];
        float4 o;
        o.x = fmaf(w00, va.x, fmaf(w01, vb.x, fmaf(w10, vc.x, w11 * vd.x)));
        o.y = fmaf(w00, va.y, fmaf(w01, vb.y, fmaf(w10, vc.y, w11 * vd.y)));
        o.z = fmaf(w00, va.z, fmaf(w01, vb.z, fmaf(w10, vc.z, w11 * vd.z)));
        o.w = fmaf(w00, va.w, fmaf(w01, vb.w, fmaf(w10, vc.w, w11 * vd.w)));
        acc[j] = o;
    }

    // affine output: 12 contiguous floats per pixel
    float4* ao = (float4*)out + (size_t)p * 3;
    ao[0] = acc[0];
    ao[1] = acc[1];
    ao[2] = acc[2];

    // res_rgb = A[:, :3] @ rgb + A[:, 3]
    float res0 = fmaf(acc[0].x, r, fmaf(acc[0].y, g, fmaf(acc[0].z, b, acc[0].w)));
    float res1 = fmaf(acc[1].x, r, fmaf(acc[1].y, g, fmaf(acc[1].z, b, acc[1].w)));
    float res2 = fmaf(acc[2].x, r, fmaf(acc[2].y, g, fmaf(acc[2].z, b, acc[2].w)));

    float* ro = out + (size_t)HW_PIX * 12 + (size_t)p * 3;
    ro[0] = res0;
    ro[1] = res1;
    ro[2] = res2;
}

extern "C" void kernel_launch(void* const* d_in, const int* in_sizes, int n_in,
                              void* d_out, int out_size, void* d_ws, size_t ws_size,
                              hipStream_t stream) {
    const float* rgb   = (const float*)d_in[0];
    const float* grids = (const float*)d_in[1];
    const int*   idx   = (const int*)d_in[2];
    float*       out   = (float*)d_out;

    dim3 grid(W_IMG / SEG, H_IMG);   // (10, 1080)
    dim3 block(SEG);
    bg_kernel<<<grid, block, 0, stream>>>(rgb, grids, idx, out);
}